// Round 10
// baseline (354.287 us; speedup 1.0000x reference)
//
#include <hip/hip_runtime.h>
#include <hip/hip_bf16.h>

// ResGraphModule on MI355X (gfx950).
//   agg = segment_sum(x[src] * (ea@W_edge), dst)   (k_bucket + k_fusedagg)
//   rel/root/res GEMMs                             (k_gemm, grid (625,3), MFMA 2-term)
//   h = relu(rel+root+b); BN stats                 (k_bnstat)
//   out = BN(h)*gamma+beta + res                   (k_finalize)
//
// R9 (resubmit — container failed twice, kernel never ran):
// fused edge-GEMM + aggregation. R8 showed k_aggregate at 41% HBM but
// ~6.2 TB/s LOGICAL stream (VMEM-path saturated) with near-compulsory
// FETCH=223MB — the only lever is removing bytes. e_mat round-trip
// (164MB write + 164MB read) eliminated: each dst-node's block gathers its
// <=64 ea rows, computes e on the spot via MFMA (edges are consumed exactly
// once -> no recompute), e-tile stays in LDS for the multiply-reduce.

#define N_NODES 20000
#define E_EDGES 320000
#define C 256
#define CE 64
#define MAXDEG 64
#define BN_EPS 1e-5f

typedef __attribute__((ext_vector_type(8))) short short8;
typedef __attribute__((ext_vector_type(8))) unsigned short ushort8;
typedef __attribute__((ext_vector_type(4))) float f32x4;
typedef __attribute__((ext_vector_type(4))) unsigned short ushort4v;

static __device__ __forceinline__ float bf2f(unsigned short u) {
    union { unsigned int i; float f; } v; v.i = (unsigned int)u << 16; return v.f;
}
static __device__ __forceinline__ unsigned short f2bf(float f) {
    __hip_bfloat16 h = __float2bfloat16(f);          // RNE
    return *reinterpret_cast<unsigned short*>(&h);
}

// ---------------------------------------------------------------- kernel W
// bf16 weights in MFMA B-fragment order:
//   wt[mat][nt=n>>4][kt=k>>5][lane=(n&15)|(((k>>3)&3)<<4)][j=k&7]
__global__ __launch_bounds__(256) void k_wprep(
    const float* __restrict__ W_rel, const float* __restrict__ W_root,
    const float* __restrict__ W_res, const float* __restrict__ W_edge,
    unsigned short* __restrict__ wt_hi, unsigned short* __restrict__ wte_hi) {
    int b = blockIdx.x, n = threadIdx.x;
    if (b < 768) {
        int m = b >> 8, k = b & 255;
        const float* W = (m == 0) ? W_rel : (m == 1) ? W_root : W_res;
        size_t o = (((size_t)m * 16 + (n >> 4)) * 8 + (k >> 5)) * 512
                 + (size_t)(((n & 15) | (((k >> 3) & 3) << 4)) * 8) + (k & 7);
        wt_hi[o] = f2bf(W[k * C + n]);
    } else {
        int k = b - 768;                         // 0..63
        size_t o = ((size_t)(n >> 4) * 2 + (k >> 5)) * 512
                 + (size_t)(((n & 15) | (((k >> 3) & 3) << 4)) * 8) + (k & 7);
        wte_hi[o] = f2bf(W_edge[k * C + n]);
    }
}

// ---------------------------------------------------------------- kernel A
__global__ void k_bucket(const int* __restrict__ ei, int* __restrict__ deg,
                         int2* __restrict__ elist2) {
    int e = blockIdx.x * blockDim.x + threadIdx.x;
    if (e < E_EDGES) {
        int d = ei[E_EDGES + e];                 // dst
        int s = ei[e];                           // src
        int slot = atomicAdd(&deg[d], 1);
        if (slot < MAXDEG) elist2[d * MAXDEG + slot] = make_int2(e, s);
    }
}

// ---------------------------------------------------------------- kernel B
// Fused edge-GEMM + aggregate. One block per dst node:
//  1) gather <=64 ea rows, stage hi/lo frag-packed (16KB)
//  2) MFMA e-tile = ea @ W_edge (2-term, rt tiles sized to actual degree)
//  3) e-tile -> LDS bf16 [64][256] (overlays frags; barriers guard)
//  4) channel-parallel: agg[node][c] = sum_r bf2f(e[r][c]) * x[src_r][c]
__global__ __launch_bounds__(256, 4) void k_fusedagg(
    const float* __restrict__ x, const float* __restrict__ ea,
    const unsigned short* __restrict__ wte_hi,
    const int* __restrict__ deg, const int2* __restrict__ elist2,
    float* __restrict__ agg) {
    __shared__ short lds[16384];                 // frag 16KB | e-tile 32KB union
    __shared__ int es[MAXDEG], ss[MAXDEG];
    const int tid = threadIdx.x;
    const int node = blockIdx.x;

    int dr = deg[node];
    const int d = dr < MAXDEG ? dr : MAXDEG;
    if (d == 0) {
        agg[(size_t)node * C + tid] = 0.f;
        return;
    }
    if (tid < d) {
        int2 p = elist2[node * MAXDEG + tid];
        es[tid] = p.x; ss[tid] = p.y;
    }
    __syncthreads();

    const int rtmax = (d + 15) >> 4;             // 1 or 2 almost always

    // stage ea rows hi/lo in frag order [rt][ks2][pl2][lane64][j8]
#pragma unroll
    for (int i = 0; i < 4; ++i) {
        int f = tid + 256 * i;                   // float4 id 0..1023
        int r = f >> 4, k4 = (f & 15) * 4;
        if (r < rtmax * 16) {
            float4 v = {0.f, 0.f, 0.f, 0.f};
            if (r < d)
                v = *reinterpret_cast<const float4*>(&ea[(size_t)es[r] * CE + k4]);
            unsigned short h0 = f2bf(v.x), h1 = f2bf(v.y), h2 = f2bf(v.z), h3 = f2bf(v.w);
            ushort4v hv = {h0, h1, h2, h3};
            ushort4v lv = {f2bf(v.x - bf2f(h0)), f2bf(v.y - bf2f(h1)),
                           f2bf(v.z - bf2f(h2)), f2bf(v.w - bf2f(h3))};
            int rt = r >> 4, ks = k4 >> 5;
            int lane = (r & 15) | (((k4 >> 3) & 3) << 4);
            int base = (((rt * 2 + ks) * 2 + 0) * 64 + lane) * 8 + (k4 & 7);
            *reinterpret_cast<ushort4v*>(&lds[base]) = hv;
            *reinterpret_cast<ushort4v*>(&lds[base + 512]) = lv;   // pl=1
        }
    }
    __syncthreads();

    const int w = tid >> 6, l = tid & 63;
    f32x4 acc[2][4];                             // [rt<=2][ct] (rtmax<=2 for
#pragma unroll                                   //  99.99% of Poisson(16) nodes)
    for (int rt = 0; rt < 2; ++rt)
#pragma unroll
        for (int ct = 0; ct < 4; ++ct) acc[rt][ct] = (f32x4){0.f, 0.f, 0.f, 0.f};
    const int rtc = rtmax < 2 ? rtmax : 2;

#pragma unroll
    for (int ks = 0; ks < 2; ++ks) {
        short8 b[4];
#pragma unroll
        for (int ct = 0; ct < 4; ++ct) {
            int nt = w * 4 + ct;
            b[ct] = *reinterpret_cast<const short8*>(&wte_hi[(size_t)(nt * 2 + ks) * 512 + l * 8]);
        }
        for (int rt = 0; rt < rtc; ++rt) {
            int base = ((rt * 2 + ks) * 2) * 512 + l * 8;
            short8 ah = *reinterpret_cast<const short8*>(&lds[base]);
            short8 al = *reinterpret_cast<const short8*>(&lds[base + 512]);
#pragma unroll
            for (int ct = 0; ct < 4; ++ct) {
                acc[rt][ct] = __builtin_amdgcn_mfma_f32_16x16x32_bf16(ah, b[ct], acc[rt][ct], 0, 0, 0);
                acc[rt][ct] = __builtin_amdgcn_mfma_f32_16x16x32_bf16(al, b[ct], acc[rt][ct], 0, 0, 0);
            }
        }
    }

    // tail tiles (rt 2,3 <-> rows 32..63): d > 32 is P ~ 1e-4; MFMA as well.
    f32x4 acc3[2][4];
    const bool deep = (rtmax > 2);
    if (deep) {
#pragma unroll
        for (int rt = 0; rt < 2; ++rt)
#pragma unroll
            for (int ct = 0; ct < 4; ++ct) acc3[rt][ct] = (f32x4){0.f, 0.f, 0.f, 0.f};
#pragma unroll
        for (int ks = 0; ks < 2; ++ks) {
            short8 b[4];
#pragma unroll
            for (int ct = 0; ct < 4; ++ct) {
                int nt = w * 4 + ct;
                b[ct] = *reinterpret_cast<const short8*>(&wte_hi[(size_t)(nt * 2 + ks) * 512 + l * 8]);
            }
            for (int rt = 2; rt < rtmax; ++rt) {
                int base = ((rt * 2 + ks) * 2) * 512 + l * 8;
                short8 ah = *reinterpret_cast<const short8*>(&lds[base]);
                short8 al = *reinterpret_cast<const short8*>(&lds[base + 512]);
#pragma unroll
                for (int ct = 0; ct < 4; ++ct) {
                    acc3[rt - 2][ct] = __builtin_amdgcn_mfma_f32_16x16x32_bf16(ah, b[ct], acc3[rt - 2][ct], 0, 0, 0);
                    acc3[rt - 2][ct] = __builtin_amdgcn_mfma_f32_16x16x32_bf16(al, b[ct], acc3[rt - 2][ct], 0, 0, 0);
                }
            }
        }
    }

    __syncthreads();                             // frags dead; e-tile overlays
    for (int rt = 0; rt < rtc; ++rt)
#pragma unroll
        for (int ct = 0; ct < 4; ++ct) {
            int col = w * 64 + ct * 16 + (l & 15);
#pragma unroll
            for (int q = 0; q < 4; ++q) {
                int r = rt * 16 + (l >> 4) * 4 + q;
                lds[r * C + col] = (short)f2bf(acc[rt][ct][q]);
            }
        }
    if (deep) {
        for (int rt = 2; rt < rtmax; ++rt)
#pragma unroll
            for (int ct = 0; ct < 4; ++ct) {
                int col = w * 64 + ct * 16 + (l & 15);
#pragma unroll
                for (int q = 0; q < 4; ++q) {
                    int r = rt * 16 + (l >> 4) * 4 + q;
                    lds[r * C + col] = (short)f2bf(acc3[rt - 2][ct][q]);
                }
            }
    }
    __syncthreads();

    // phase 4: channel-parallel multiply-reduce; x loads batched 4-deep
    const int c = tid;
    float accv = 0.f;
    for (int i = 0; i < d; i += 4) {
        int m = d - i;                           // block-uniform
        float xv[4], ev[4];
#pragma unroll
        for (int j = 0; j < 4; ++j) {
            if (j < m) {
                xv[j] = x[(size_t)ss[i + j] * C + c];
                ev[j] = bf2f((unsigned short)lds[(i + j) * C + c]);
            } else { xv[j] = 0.f; ev[j] = 0.f; }
        }
#pragma unroll
        for (int j = 0; j < 4; ++j) accv += ev[j] * xv[j];
    }
    agg[(size_t)node * C + c] = accv;
}

// ---------------------------------------------------------------- kernel D
// One matrix per blockIdx.y: 0: rel=agg@W_rel, 1: root=x@W_root, 2: res=x@W_res.
// Block = 32 nodes x 256 cols. A-frags hi/lo packed lane-linear in LDS (32KB,
// 4 blocks/CU). B: 4 x 16B loads/ks/wave from fragment-packed weights.
// No barriers in the K-loop; 2-term MFMA.
__global__ __launch_bounds__(256, 4) void k_gemm(
    const float* __restrict__ aggt, const float* __restrict__ x,
    const unsigned short* __restrict__ wt_hi,
    float* __restrict__ g_rel, float* __restrict__ g_root,
    float* __restrict__ g_res) {
    __shared__ short AB[16384];                  // [rt2][ks8][pl2][lane64][j8]
    const int tid = threadIdx.x;
    const int n0 = blockIdx.x * 32;
    const int mat = blockIdx.y;
    const float* Asrc = (mat == 0) ? aggt : x;
    float* dst = (mat == 0) ? g_rel : (mat == 1) ? g_root : g_res;

#pragma unroll
    for (int i = 0; i < 8; ++i) {
        int f = tid + 256 * i;                   // float4 id 0..2047
        int r = f >> 6, k4 = (f & 63) * 4;
        float4 v = *reinterpret_cast<const float4*>(&Asrc[(size_t)(n0 + r) * C + k4]);
        unsigned short h0 = f2bf(v.x), h1 = f2bf(v.y), h2 = f2bf(v.z), h3 = f2bf(v.w);
        ushort4v hv = {h0, h1, h2, h3};
        ushort4v lv = {f2bf(v.x - bf2f(h0)), f2bf(v.y - bf2f(h1)),
                       f2bf(v.z - bf2f(h2)), f2bf(v.w - bf2f(h3))};
        int rt = r >> 4, ks = k4 >> 5;
        int lane = (r & 15) | (((k4 >> 3) & 3) << 4);
        int base = (((rt * 8 + ks) * 2 + 0) * 64 + lane) * 8 + (k4 & 7);
        *reinterpret_cast<ushort4v*>(&AB[base]) = hv;
        *reinterpret_cast<ushort4v*>(&AB[base + 512]) = lv;    // pl=1
    }
    __syncthreads();

    const int w = tid >> 6, l = tid & 63;
    f32x4 acc[2][4];                             // [rt][ct]
#pragma unroll
    for (int rt = 0; rt < 2; ++rt)
#pragma unroll
        for (int ct = 0; ct < 4; ++ct) acc[rt][ct] = (f32x4){0.f, 0.f, 0.f, 0.f};

    const unsigned short* wbase = wt_hi + (size_t)mat * 16 * 8 * 512;

#pragma unroll
    for (int ks = 0; ks < 8; ++ks) {
        short8 b[4];
#pragma unroll
        for (int ct = 0; ct < 4; ++ct) {
            int nt = w * 4 + ct;
            b[ct] = *reinterpret_cast<const short8*>(&wbase[(size_t)(nt * 8 + ks) * 512 + l * 8]);
        }
        short8 ah[2], al[2];
#pragma unroll
        for (int rt = 0; rt < 2; ++rt) {
            int base = ((rt * 8 + ks) * 2) * 512 + l * 8;
            ah[rt] = *reinterpret_cast<const short8*>(&AB[base]);
            al[rt] = *reinterpret_cast<const short8*>(&AB[base + 512]);
        }
#pragma unroll
        for (int ct = 0; ct < 4; ++ct)
#pragma unroll
            for (int rt = 0; rt < 2; ++rt) {
                acc[rt][ct] = __builtin_amdgcn_mfma_f32_16x16x32_bf16(ah[rt], b[ct], acc[rt][ct], 0, 0, 0);
                acc[rt][ct] = __builtin_amdgcn_mfma_f32_16x16x32_bf16(al[rt], b[ct], acc[rt][ct], 0, 0, 0);
            }
    }

#pragma unroll
    for (int ct = 0; ct < 4; ++ct) {
        int col = w * 64 + ct * 16 + (l & 15);
#pragma unroll
        for (int rt = 0; rt < 2; ++rt)
#pragma unroll
            for (int q = 0; q < 4; ++q) {
                int node = n0 + rt * 16 + (l >> 4) * 4 + q;
                dst[(size_t)node * C + col] = acc[rt][ct][q];
            }
    }
}

// ---------------------------------------------------------------- kernel D2
// h = relu(rel + root + bias); accumulate per-channel sum/sumsq.
__global__ __launch_bounds__(256) void k_bnstat(
    const float* __restrict__ g_rel, const float* __restrict__ g_root,
    const float* __restrict__ b_rel, float* __restrict__ chsum,
    float* __restrict__ chsumsq) {
    __shared__ float2 red[4 * 256];              // 8KB
    const int tid = threadIdx.x;
    const int c0 = (tid & 63) * 4, rg = tid >> 6;
    const int base = blockIdx.x * 32;
    float4 b4 = *reinterpret_cast<const float4*>(&b_rel[c0]);
    float4 s1 = {0.f, 0.f, 0.f, 0.f}, s2 = {0.f, 0.f, 0.f, 0.f};
#pragma unroll
    for (int i = 0; i < 8; ++i) {
        size_t row = (size_t)(base + rg * 8 + i) * C + c0;
        float4 hr = *reinterpret_cast<const float4*>(&g_rel[row]);
        float4 ho = *reinterpret_cast<const float4*>(&g_root[row]);
        float4 h;
        h.x = fmaxf(hr.x + ho.x + b4.x, 0.f);
        h.y = fmaxf(hr.y + ho.y + b4.y, 0.f);
        h.z = fmaxf(hr.z + ho.z + b4.z, 0.f);
        h.w = fmaxf(hr.w + ho.w + b4.w, 0.f);
        s1.x += h.x; s1.y += h.y; s1.z += h.z; s1.w += h.w;
        s2.x += h.x * h.x; s2.y += h.y * h.y;
        s2.z += h.z * h.z; s2.w += h.w * h.w;
    }
    red[rg * 256 + c0 + 0] = make_float2(s1.x, s2.x);
    red[rg * 256 + c0 + 1] = make_float2(s1.y, s2.y);
    red[rg * 256 + c0 + 2] = make_float2(s1.z, s2.z);
    red[rg * 256 + c0 + 3] = make_float2(s1.w, s2.w);
    __syncthreads();
    float a = 0.f, bsum = 0.f;
#pragma unroll
    for (int g = 0; g < 4; ++g) {
        float2 v = red[g * 256 + tid];
        a += v.x; bsum += v.y;
    }
    atomicAdd(&chsum[tid], a);
    atomicAdd(&chsumsq[tid], bsum);
}

// ---------------------------------------------------------------- kernel E
// out = BN(relu(rel+root+bias))*gamma + beta + res   (res already in out)
__global__ __launch_bounds__(256) void k_finalize(
    const float* __restrict__ g_rel, const float* __restrict__ g_root,
    const float* __restrict__ b_rel, const float* __restrict__ chsum,
    const float* __restrict__ chsumsq, const float* __restrict__ gamma,
    const float* __restrict__ beta, float* out) {
    const float invN = 1.f / (float)N_NODES;
    int i = (blockIdx.x * blockDim.x + threadIdx.x) * 4;
    if (i >= N_NODES * C) return;
    int c = i & (C - 1);
    float4 hr = *reinterpret_cast<const float4*>(&g_rel[i]);
    float4 ho = *reinterpret_cast<const float4*>(&g_root[i]);
    float4 b4 = *reinterpret_cast<const float4*>(&b_rel[c]);
    float4 rv = *reinterpret_cast<const float4*>(&out[i]);
    float4 o;
    {
        float h = fmaxf(hr.x + ho.x + b4.x, 0.f);
        float m = chsum[c + 0] * invN;
        float v = chsumsq[c + 0] * invN - m * m;
        o.x = (h - m) * rsqrtf(v + BN_EPS) * gamma[c + 0] + beta[c + 0] + rv.x;
    }
    {
        float h = fmaxf(hr.y + ho.y + b4.y, 0.f);
        float m = chsum[c + 1] * invN;
        float v = chsumsq[c + 1] * invN - m * m;
        o.y = (h - m) * rsqrtf(v + BN_EPS) * gamma[c + 1] + beta[c + 1] + rv.y;
    }
    {
        float h = fmaxf(hr.z + ho.z + b4.z, 0.f);
        float m = chsum[c + 2] * invN;
        float v = chsumsq[c + 2] * invN - m * m;
        o.z = (h - m) * rsqrtf(v + BN_EPS) * gamma[c + 2] + beta[c + 2] + rv.z;
    }
    {
        float h = fmaxf(hr.w + ho.w + b4.w, 0.f);
        float m = chsum[c + 3] * invN;
        float v = chsumsq[c + 3] * invN - m * m;
        o.w = (h - m) * rsqrtf(v + BN_EPS) * gamma[c + 3] + beta[c + 3] + rv.w;
    }
    *reinterpret_cast<float4*>(&out[i]) = o;
}

// ---------------------------------------------------------------- launch
extern "C" void kernel_launch(void* const* d_in, const int* in_sizes, int n_in,
                              void* d_out, int out_size, void* d_ws, size_t ws_size,
                              hipStream_t stream) {
    const float* x      = (const float*)d_in[0];
    const int*   ei     = (const int*)  d_in[1];
    const float* ea     = (const float*)d_in[2];
    const float* W_edge = (const float*)d_in[3];
    const float* W_rel  = (const float*)d_in[4];
    const float* b_rel  = (const float*)d_in[5];
    const float* W_root = (const float*)d_in[6];
    const float* gamma  = (const float*)d_in[7];
    const float* beta   = (const float*)d_in[8];
    const float* W_res  = (const float*)d_in[9];
    float* out = (float*)d_out;

    // ws layout:
    //   aggt    : N*C fp32
    //   chsum   : 256, chsumsq: 256, deg: N int   (one memset)
    //   elist2  : N*64 int2
    //   g_rel   : N*C fp32 ; g_root : N*C fp32
    //   wte_hi  : 16K bf16 ; wt_hi : 3*64K bf16  (fragment-packed)
    float* ws      = (float*)d_ws;
    float* aggt    = ws;
    float* chsum   = ws + (size_t)N_NODES * C;
    float* chsumsq = chsum + C;
    int*   deg     = (int*)(chsumsq + C);
    int2*  elist2  = (int2*)(deg + N_NODES);
    float* g_rel   = (float*)(elist2 + (size_t)N_NODES * MAXDEG);
    float* g_root  = g_rel + (size_t)N_NODES * C;
    unsigned short* wte_hi = (unsigned short*)(g_root + (size_t)N_NODES * C);
    unsigned short* wt_hi  = wte_hi + C * CE;
    size_t need = (char*)(wt_hi + 3 * C * C) - (char*)d_ws;
    if (ws_size < need) return;

    hipMemsetAsync(chsum, 0, 2 * C * sizeof(float) + N_NODES * sizeof(int), stream);

    k_wprep<<<832, 256, 0, stream>>>(W_rel, W_root, W_res, W_edge, wt_hi, wte_hi);
    k_bucket<<<(E_EDGES + 255) / 256, 256, 0, stream>>>(ei, deg, elist2);
    k_fusedagg<<<N_NODES, 256, 0, stream>>>(x, ea, wte_hi, deg, elist2, aggt);
    k_gemm<<<dim3(N_NODES / 32, 3), 256, 0, stream>>>(aggt, x, wt_hi,
                                                      g_rel, g_root, out);
    k_bnstat<<<N_NODES / 32, 256, 0, stream>>>(g_rel, g_root, b_rel, chsum, chsumsq);
    k_finalize<<<(N_NODES * C / 4 + 255) / 256, 256, 0, stream>>>(
        g_rel, g_root, b_rel, chsum, chsumsq, gamma, beta, out);
}